// Round 7
// baseline (169.379 us; speedup 1.0000x reference)
//
#include <hip/hip_runtime.h>
#include <hip/hip_bf16.h>
#include <math.h>
#include <stdint.h>

#define NROWS 1000000
#define NCOLS 100
#define NBINS 20
#define NB    19       // bin boundaries
#define W     50000u   // rows per bin
#define NH    2049     // buckets: 0 = catch-all (<0.5), 1..2048 = [0.5,1) in 2^-12 steps

// ---------- ws layout (dword offsets) ----------
#define HIST_DW 0u       // len 2052
#define BINS_DW 2052u    // len 80 dw = 40 doubles (byte 8208, 8-aligned)
#define ZERO_DW 2132u    // hist+bins zeroed inside k1
#define CONF_DW 2136u    // len 1000000 (byte 8544 = 534*16, 16B-aligned); sign bit = accuracy

__device__ __forceinline__ unsigned int bucket_of(unsigned int bits) {
    // bits = positive-f32 pattern. conf < 0.5 -> 0 (catch-all).
    if (bits < 0x3F000000u) return 0u;
    unsigned int t = (bits >> 12) - 258048u + 1u;   // 1..2048 for [0.5,1)
    return t > 2048u ? 2048u : t;
}

// ---------- K1: wave-cooperative row max/argmax, 4x unrolled for MLP -------
// Each 32-lane half-wave handles one row (lanes 0-24 load 25 float4).
// 4 row-pairs per wave iteration: all 4 loads issued independently before
// any reduce -> 4 outstanding dwordx4 per wave (32/SIMD) hides ~900cy HBM
// latency and makes the kernel BW-bound instead of latency-bound.
__global__ __launch_bounds__(256) void k1_rowmax(const float* __restrict__ x,
                                                 const int* __restrict__ labels,
                                                 float* __restrict__ conf,
                                                 unsigned int* __restrict__ zero_region) {
    int gtid = blockIdx.x * 256 + threadIdx.x;
    if (gtid < (int)ZERO_DW) zero_region[gtid] = 0u;   // hist + bins

    int wave = gtid >> 6;
    int lane = threadIdx.x & 63;
    int half = lane >> 5;
    int l    = lane & 31;
    int nwaves = (gridDim.x * 256) >> 6;

    for (int rp0 = wave * 4; rp0 < NROWS / 2; rp0 += nwaves * 4) {
        float4 v[4];
        // issue all independent loads first
        #pragma unroll
        for (int u = 0; u < 4; u++) {
            int rp = rp0 + u;
            if (rp < NROWS / 2 && l < 25) {
                int row = rp * 2 + half;
                v[u] = reinterpret_cast<const float4*>(x + (size_t)row * NCOLS)[l];
            }
        }
        // then reduce each
        #pragma unroll
        for (int u = 0; u < 4; u++) {
            int rp = rp0 + u;
            if (rp >= NROWS / 2) break;
            int row = rp * 2 + half;
            float best = -1.0f;
            int bi = 999;
            if (l < 25) {
                best = v[u].x; bi = 4 * l;
                if (v[u].y > best) { best = v[u].y; bi = 4 * l + 1; }
                if (v[u].z > best) { best = v[u].z; bi = 4 * l + 2; }
                if (v[u].w > best) { best = v[u].w; bi = 4 * l + 3; }
            }
            #pragma unroll
            for (int mask = 16; mask >= 1; mask >>= 1) {
                float ov = __shfl_xor(best, mask);
                int   oi = __shfl_xor(bi,   mask);
                if (ov > best || (ov == best && oi < bi)) { best = ov; bi = oi; }
            }
            if (l == 0) {
                unsigned int cb = __float_as_uint(best);
                if (bi == labels[row]) cb |= 0x80000000u;
                conf[row] = __uint_as_float(cb);
            }
        }
    }
}

// ---------- K2: 2049-bucket histogram, per-block LDS ----------
__global__ __launch_bounds__(512) void k2_hist(const float* __restrict__ conf,
                                               unsigned int* __restrict__ hist) {
    __shared__ unsigned int lh[NH];
    for (int i = threadIdx.x; i < NH; i += 512) lh[i] = 0u;
    __syncthreads();
    const uint4* c4 = reinterpret_cast<const uint4*>(conf);
    int stride = gridDim.x * 512;
    for (int i = blockIdx.x * 512 + threadIdx.x; i < NROWS / 4; i += stride) {
        uint4 v = c4[i];
        atomicAdd(&lh[bucket_of(v.x & 0x7FFFFFFFu)], 1u);
        atomicAdd(&lh[bucket_of(v.y & 0x7FFFFFFFu)], 1u);
        atomicAdd(&lh[bucket_of(v.z & 0x7FFFFFFFu)], 1u);
        atomicAdd(&lh[bucket_of(v.w & 0x7FFFFFFFu)], 1u);
    }
    __syncthreads();
    for (int i = threadIdx.x; i < NH; i += 512) {
        unsigned int c = lh[i];
        if (c) atomicAdd(&hist[i], c);
    }
}

// ---------- K3: per-block redundant scan+bounds, then split-accumulate ----
__global__ __launch_bounds__(256) void k3_accum(const float* __restrict__ conf,
                                                const unsigned int* __restrict__ hist,
                                                double* __restrict__ bins) {
    __shared__ unsigned int ptab[NH];   // prefix, later |= (slot+1)<<24 on boundary buckets
    __shared__ unsigned int s[256];
    __shared__ unsigned int bndS[NB];
    __shared__ float sFr[NB];
    __shared__ float sc[4][NBINS], sa[4][NBINS];
    int tid = threadIdx.x;

    // --- scan hist (2049) into ptab ---
    unsigned int loc[9];
    unsigned int tot = 0;
    int base = tid * 9;
    #pragma unroll
    for (int k = 0; k < 9; k++) {
        int idx = base + k;
        unsigned int v = (idx < NH) ? hist[idx] : 0u;
        loc[k] = tot; tot += v;
    }
    s[tid] = tot; __syncthreads();
    for (int off = 1; off < 256; off <<= 1) {
        unsigned int v = (tid >= off) ? s[tid - off] : 0u;
        __syncthreads();
        s[tid] += v;
        __syncthreads();
    }
    unsigned int excl = s[tid] - tot;
    #pragma unroll
    for (int k = 0; k < 9; k++) {
        int idx = base + k;
        if (idx < NH) ptab[idx] = excl + loc[k];
    }
    for (int i = tid; i < 4 * NBINS; i += 256) { (&sc[0][0])[i] = 0.f; (&sa[0][0])[i] = 0.f; }
    __syncthreads();

    // --- phase A: locate boundaries on the CLEAN prefix, save fr ---
    if (tid < NB) {
        unsigned int r = (unsigned int)(tid + 1) * W;
        int lo = 0, hi = NH - 1;
        while (lo < hi) {
            int mid = (lo + hi + 1) >> 1;
            if (ptab[mid] <= r) lo = mid; else hi = mid - 1;
        }
        unsigned int p = ptab[lo];
        if (p < r) {
            unsigned int cnt = ((lo + 1 < NH) ? ptab[lo + 1] : (unsigned int)NROWS) - p;
            bndS[tid] = (unsigned int)lo;
            sFr[tid]  = (float)(r - p) / (float)cnt;
        } else {
            bndS[tid] = 0xFFFFFFFFu;
        }
    }
    __syncthreads();
    // --- phase B: mark boundary buckets ---
    if (tid < NB && bndS[tid] != 0xFFFFFFFFu)
        ptab[bndS[tid]] |= (unsigned int)(tid + 1) << 24;
    __syncthreads();

    // --- main pass ---
    int wid = tid >> 6;
    const uint4* c4 = reinterpret_cast<const uint4*>(conf);
    int stride = gridDim.x * 256;
    for (int i = blockIdx.x * 256 + tid; i < NROWS / 4; i += stride) {
        uint4 q = c4[i];
        unsigned int bs[4] = { q.x, q.y, q.z, q.w };
        #pragma unroll
        for (int j = 0; j < 4; j++) {
            unsigned int raw = bs[j];
            float a = (float)(raw >> 31);
            unsigned int bits = raw & 0x7FFFFFFFu;
            float c = __uint_as_float(bits);
            unsigned int e = ptab[bucket_of(bits)];
            unsigned int t = e >> 24;
            if (t == 0u) {
                unsigned int bin = (e & 0xFFFFFFu) / W;
                atomicAdd(&sc[wid][bin], c); atomicAdd(&sa[wid][bin], a);
            } else {
                float fr = sFr[t - 1];
                atomicAdd(&sc[wid][t - 1], c * fr);
                atomicAdd(&sc[wid][t],     c * (1.f - fr));
                atomicAdd(&sa[wid][t - 1], a * fr);
                atomicAdd(&sa[wid][t],     a * (1.f - fr));
            }
        }
    }
    __syncthreads();
    if (tid < NBINS) {
        float tc = sc[0][tid] + sc[1][tid] + sc[2][tid] + sc[3][tid];
        float ta = sa[0][tid] + sa[1][tid] + sa[2][tid] + sa[3][tid];
        atomicAdd(&bins[tid],         (double)tc);
        atomicAdd(&bins[NBINS + tid], (double)ta);
    }
}

// ---------- K4: finalize ----------
__global__ __launch_bounds__(64) void k4_final(const double* __restrict__ bins,
                                               float* __restrict__ out) {
    if (threadIdx.x == 0) {
        double ece = 0.0;
        for (int b = 0; b < NBINS; b++) {
            double avc = bins[b] / (double)W;
            double ava = bins[NBINS + b] / (double)W;
            ece += fabs(avc - ava);
            out[1 + b] = (float)ava;
        }
        out[0] = (float)(ece * ((double)W / (double)NROWS));
    }
}

extern "C" void kernel_launch(void* const* d_in, const int* in_sizes, int n_in,
                              void* d_out, int out_size, void* d_ws, size_t ws_size,
                              hipStream_t stream) {
    const float* x      = (const float*)d_in[0];
    const int*   labels = (const int*)d_in[1];
    float*       out    = (float*)d_out;
    unsigned int* wd    = (unsigned int*)d_ws;

    unsigned int* hist = wd + HIST_DW;
    double*       bins = (double*)(wd + BINS_DW);
    float*        conf = (float*)(wd + CONF_DW);

    k1_rowmax<<<2048, 256, 0, stream>>>(x, labels, conf, wd);
    k2_hist  <<<128, 512, 0, stream>>>(conf, hist);
    k3_accum <<<512, 256, 0, stream>>>(conf, hist, bins);
    k4_final <<<1, 64, 0, stream>>>(bins, out);
}